// Round 7
// baseline (348.016 us; speedup 1.0000x reference)
//
#include <hip/hip_runtime.h>

// MaskedAttentionHead: y = softmax((q@Wq+bq)(k@Wk+bk)^T/8 * m_row) @ (v@Wv+bv)
// B=4 S=4096 D=1024 DK=64. fp32 in/out, bf16 MFMA intermediates, fp32 accum.
// m/8*log2e folded into Q-proj -> mask-free exp2 flash attn, no max-subtract
// (scores statically bounded), additive split-K.
// R7: kill vmcnt(0) barrier drains (R6 lesson: __syncthreads = s_waitcnt
// vmcnt(0) -> prefetch dead on arrival, 1.4 TB/s latency-bound).
//  - proj: double-buffered LDS + RAW s_barrier (lgkmcnt only) -> global loads
//    stay in flight a full iteration.
//  - attn: barrier-free; K/V frags loaded direct from global (L1-resident
//    8KB tiles), wave-private P LDS only; SPLITS=8.

typedef __attribute__((ext_vector_type(8))) short short8;   // 8 bf16 = MFMA A/B frag
typedef __attribute__((ext_vector_type(4))) float float4v;  // MFMA C/D frag
typedef __attribute__((ext_vector_type(4))) unsigned int uint4v;

#define DEV static __device__ __forceinline__

DEV unsigned short f2bf(float f) {
  unsigned int x; __builtin_memcpy(&x, &f, 4);
  x += 0x7fff + ((x >> 16) & 1);  // round-to-nearest-even
  return (unsigned short)(x >> 16);
}

// workgroup barrier WITHOUT vmem drain: LDS visibility needs lgkmcnt only.
DEV void lds_barrier() {
  __asm__ volatile("s_waitcnt lgkmcnt(0)\n\ts_barrier" ::: "memory");
}

// ---------------- kernel 1: W transpose (3 x [1024,64] -> [64,1024] bf16) ---
__global__ __launch_bounds__(256) void transpose_w(
    const float* __restrict__ Wq, const float* __restrict__ Wk,
    const float* __restrict__ Wv, unsigned short* __restrict__ WT) {
  int idx = blockIdx.x * 256 + threadIdx.x;   // over 3*1024*64
  int p = idx >> 16;
  int r = idx & 65535;            // r = k*64 + d  (coalesced read)
  int kk = r >> 6, d = r & 63;
  const float* W = (p == 0) ? Wq : (p == 1) ? Wk : Wv;
  WT[p * 65536 + d * 1024 + kk] = f2bf(W[r]);
}

// ---------------- kernel 2: fused projections (dbuf LDS, raw barrier) -------
// p=0: qs[b,s,d]  = (q@Wq+bq) * m[b,s]/8 * log2(e)   (row-major, bf16)
// p=1: kh[b,s,d]  = k@Wk+bk                           (row-major)
// p=2: vhT[b,d,s] = (v@Wv+bv)^T   (transposed via swapped MFMA operand roles)
__global__ __launch_bounds__(256) void proj_kernel(
    const float* __restrict__ xq, const float* __restrict__ xk,
    const float* __restrict__ xv, const float* __restrict__ mmask,
    const float* __restrict__ bq, const float* __restrict__ bk,
    const float* __restrict__ bv, const unsigned short* __restrict__ WT,
    unsigned short* __restrict__ qs, unsigned short* __restrict__ khh,
    unsigned short* __restrict__ vhT) {
  constexpr int LDSTR = 72;   // 64+8: 16B-aligned rows, <=2-way bank alias
  __shared__ __align__(16) unsigned short Xs[2][64 * LDSTR];
  __shared__ __align__(16) unsigned short Ws[2][64 * LDSTR];

  const int p = blockIdx.x >> 8;        // projection id
  const int rt = blockIdx.x & 255;      // 64-row tile id
  const int row0 = rt * 64;             // flat (b,s) row in [0,16384)
  const int t = threadIdx.x;
  const int w = t >> 6, ln = t & 63;
  const int lr = ln & 15, quad = ln >> 4;

  const float* X = (p == 0) ? xq : (p == 1) ? xk : xv;
  const unsigned short* WTp = WT + p * 65536;
  const float* Xbase = X + (size_t)row0 * 1024;

  float4v acc[4];
#pragma unroll
  for (int i = 0; i < 4; ++i) acc[i] = (float4v){0.f, 0.f, 0.f, 0.f};

  const int srow = t >> 2;            // staging: 4 threads/row, 16 elems each
  const int scol = (t & 3) * 16;

  float4v xr[2][4];                   // prefetch regs: X 64B/thread (fp32)
  uint4v wr[2][2];                    //                W 32B/thread (bf16)

#define PISSUE(kc_, b_)                                                    \
  {                                                                        \
    const int c0_ = (kc_) * 64 + scol;                                     \
    const float* xs_ = Xbase + (size_t)srow * 1024 + c0_;                  \
    xr[b_][0] = *(const float4v*)xs_;                                      \
    xr[b_][1] = *(const float4v*)(xs_ + 4);                                \
    xr[b_][2] = *(const float4v*)(xs_ + 8);                                \
    xr[b_][3] = *(const float4v*)(xs_ + 12);                               \
    const unsigned short* wsp_ = WTp + (size_t)srow * 1024 + c0_;          \
    wr[b_][0] = *(const uint4v*)wsp_;                                      \
    wr[b_][1] = *(const uint4v*)(wsp_ + 8);                                \
  }

  PISSUE(0, 0);
#pragma unroll
  for (int kc = 0; kc < 16; ++kc) {   // K=1024 in 64-chunks
    const int b = kc & 1;
    if (kc < 15) PISSUE(kc + 1, b ^ 1);   // stays in flight through barrier

    // regs -> LDS (convert X to bf16); waits vmcnt only down to this buf's loads
    unsigned short tmp[16];
#pragma unroll
    for (int i = 0; i < 4; ++i)
#pragma unroll
      for (int j = 0; j < 4; ++j) tmp[i * 4 + j] = f2bf(xr[b][i][j]);
    *(uint4v*)&Xs[b][srow * LDSTR + scol] = *(const uint4v*)&tmp[0];
    *(uint4v*)&Xs[b][srow * LDSTR + scol + 8] = *(const uint4v*)&tmp[8];
    *(uint4v*)&Ws[b][srow * LDSTR + scol] = wr[b][0];
    *(uint4v*)&Ws[b][srow * LDSTR + scol + 8] = wr[b][1];

    lds_barrier();   // single raw barrier per iter (dbuf makes this race-free)

    if (p < 2) {
      // D[s][d] = X @ W : A-rows from Xs, B-frag = WT rows
#pragma unroll
      for (int ks = 0; ks < 2; ++ks) {
        short8 af = *(const short8*)&Xs[b][(w * 16 + lr) * LDSTR + ks * 32 + quad * 8];
#pragma unroll
        for (int ct = 0; ct < 4; ++ct) {
          short8 bf = *(const short8*)&Ws[b][(ct * 16 + lr) * LDSTR + ks * 32 + quad * 8];
          acc[ct] = __builtin_amdgcn_mfma_f32_16x16x32_bf16(af, bf, acc[ct], 0, 0, 0);
        }
      }
    } else {
      // D[d][s] = WT @ X^T : A-rows from Ws, B-frag = X rows
#pragma unroll
      for (int ks = 0; ks < 2; ++ks) {
        short8 af = *(const short8*)&Ws[b][(w * 16 + lr) * LDSTR + ks * 32 + quad * 8];
#pragma unroll
        for (int ct = 0; ct < 4; ++ct) {
          short8 bf = *(const short8*)&Xs[b][(ct * 16 + lr) * LDSTR + ks * 32 + quad * 8];
          acc[ct] = __builtin_amdgcn_mfma_f32_16x16x32_bf16(af, bf, acc[ct], 0, 0, 0);
        }
      }
    }
  }
#undef PISSUE

  // epilogues; C/D layout: col = lr, row = quad*4 + reg
  if (p == 0) {
    const float L2E8 = 1.4426950408889634f * 0.125f;  // log2(e)/sqrt(64)
#pragma unroll
    for (int r = 0; r < 4; ++r) {
      int sg = row0 + w * 16 + quad * 4 + r;
      float mv = mmask[sg] * L2E8;
#pragma unroll
      for (int ct = 0; ct < 4; ++ct) {
        int d = ct * 16 + lr;
        qs[(size_t)sg * 64 + d] = f2bf((acc[ct][r] + bq[d]) * mv);
      }
    }
  } else if (p == 1) {
#pragma unroll
    for (int r = 0; r < 4; ++r) {
      int sg = row0 + w * 16 + quad * 4 + r;
#pragma unroll
      for (int ct = 0; ct < 4; ++ct) {
        int d = ct * 16 + lr;
        khh[(size_t)sg * 64 + d] = f2bf(acc[ct][r] + bk[d]);
      }
    }
  } else {
    int b = row0 >> 12, sloc = row0 & 4095;
#pragma unroll
    for (int r = 0; r < 4; ++r) {
      int d = w * 16 + quad * 4 + r;
      float bias = bv[d];
#pragma unroll
      for (int ct = 0; ct < 4; ++ct) {
        int sg = sloc + ct * 16 + lr;
        vhT[(size_t)b * 64 * 4096 + (size_t)d * 4096 + sg] = f2bf(acc[ct][r] + bias);
      }
    }
  }
}

// ---------------- kernel 3: split-K flash attention (barrier-free) ----------
// grid = splits * B * (S/64); block = 4 fully-independent waves, each owns
// 16 q-rows. K/V fragments loaded straight from global (tiles L1-resident);
// only wave-private P-transpose LDS. No __syncthreads anywhere.
__global__ __launch_bounds__(256) void attn_split(
    const unsigned short* __restrict__ qs, const unsigned short* __restrict__ khh,
    const unsigned short* __restrict__ vhT, float* __restrict__ O_part,
    float* __restrict__ L_part, int nkt) {
  constexpr int LDSTR = 72;
  __shared__ __align__(16) unsigned short Ps[4 * 16 * LDSTR];   // per-wave P

  const int split = blockIdx.x >> 8;
  const int rest  = blockIdx.x & 255;
  const int b = rest >> 6;
  const int s0 = (rest & 63) * 64;
  const int t = threadIdx.x, w = t >> 6, ln = t & 63;
  const int lr = ln & 15, quad = ln >> 4;
  const int key0 = split * nkt * 64;

  // Q A-fragments, held in registers for the whole kernel
  const size_t qrow = (size_t)(b * 4096 + s0 + w * 16 + lr) * 64;
  short8 qf0 = *(const short8*)&qs[qrow + quad * 8];
  short8 qf1 = *(const short8*)&qs[qrow + 32 + quad * 8];

  float Lacc[4] = {0.f, 0.f, 0.f, 0.f};
  float4v O[4];
#pragma unroll
  for (int i = 0; i < 4; ++i) O[i] = (float4v){0.f, 0.f, 0.f, 0.f};

  const unsigned short* Kg = khh + (size_t)b * 4096 * 64;
  const unsigned short* Vg = vhT + (size_t)b * 64 * 4096;
  unsigned short* Pw = Ps + w * 16 * LDSTR;

  for (int kt = 0; kt < nkt; ++kt) {
    const int k0 = key0 + kt * 64;

    // S = Q K^T: K-fragments direct from global (row = key, 128B rows)
    float4v sc[4];
#pragma unroll
    for (int ct = 0; ct < 4; ++ct) {
      const unsigned short* kr = &Kg[(size_t)(k0 + ct * 16 + lr) * 64 + quad * 8];
      short8 kf0 = *(const short8*)kr;
      short8 kf1 = *(const short8*)(kr + 32);
      sc[ct] = (float4v){0.f, 0.f, 0.f, 0.f};
      sc[ct] = __builtin_amdgcn_mfma_f32_16x16x32_bf16(qf0, kf0, sc[ct], 0, 0, 0);
      sc[ct] = __builtin_amdgcn_mfma_f32_16x16x32_bf16(qf1, kf1, sc[ct], 0, 0, 0);
    }

    // P = exp2(S): per-lane row partials, wave-private LDS transpose
#pragma unroll
    for (int ct = 0; ct < 4; ++ct)
#pragma unroll
      for (int r = 0; r < 4; ++r) {
        float pv = exp2f(sc[ct][r]);
        Lacc[r] += pv;
        Pw[(quad * 4 + r) * LDSTR + ct * 16 + lr] = f2bf(pv);
      }
    __asm__ volatile("s_waitcnt lgkmcnt(0)" ::: "memory");  // wave-local order

    short8 pf0 = *(const short8*)&Pw[lr * LDSTR + quad * 8];
    short8 pf1 = *(const short8*)&Pw[lr * LDSTR + 32 + quad * 8];
#pragma unroll
    for (int dt = 0; dt < 4; ++dt) {
      const unsigned short* vr = &Vg[(size_t)(dt * 16 + lr) * 4096 + k0 + quad * 8];
      short8 vf0 = *(const short8*)vr;
      short8 vf1 = *(const short8*)(vr + 32);
      O[dt] = __builtin_amdgcn_mfma_f32_16x16x32_bf16(pf0, vf0, O[dt], 0, 0, 0);
      O[dt] = __builtin_amdgcn_mfma_f32_16x16x32_bf16(pf1, vf1, O[dt], 0, 0, 0);
    }
  }

  // reduce L over the 16 lanes of each quad (once per kernel)
#pragma unroll
  for (int r = 0; r < 4; ++r) {
    float s = Lacc[r];
    s += __shfl_xor(s, 1);
    s += __shfl_xor(s, 2);
    s += __shfl_xor(s, 4);
    s += __shfl_xor(s, 8);
    Lacc[r] = s;
  }

  // store partials; C/D layout: col=lr (d), row=quad*4+r (q-row)
#pragma unroll
  for (int r = 0; r < 4; ++r) {
    int prow = b * 4096 + s0 + w * 16 + quad * 4 + r;
    size_t obase = ((size_t)split * 16384 + prow) * 64;
#pragma unroll
    for (int dt = 0; dt < 4; ++dt)
      O_part[obase + dt * 16 + lr] = O[dt][r];
    if (lr == 0) L_part[(size_t)split * 16384 + prow] = Lacc[r];
  }
}

// ---------------- kernel 4: split-K combine ---------------------------------
__global__ __launch_bounds__(256) void attn_reduce(
    const float* __restrict__ O_part, const float* __restrict__ L_part,
    float* __restrict__ out, int splits) {
  size_t idx = (size_t)blockIdx.x * 256 + threadIdx.x;  // over 16384*64
  size_t row = idx >> 6;
  float l = 0.f, o = 0.f;
  for (int s = 0; s < splits; ++s) {
    l += L_part[(size_t)s * 16384 + row];
    o += O_part[idx + (size_t)s * 16384 * 64];
  }
  out[idx] = o / l;
}

// ---------------- launch ----------------------------------------------------
extern "C" void kernel_launch(void* const* d_in, const int* in_sizes, int n_in,
                              void* d_out, int out_size, void* d_ws, size_t ws_size,
                              hipStream_t stream) {
  const float* q  = (const float*)d_in[0];
  const float* k  = (const float*)d_in[1];
  const float* v  = (const float*)d_in[2];
  const float* m  = (const float*)d_in[3];
  const float* Wq = (const float*)d_in[4];
  const float* bq = (const float*)d_in[5];
  const float* Wk = (const float*)d_in[6];
  const float* bk = (const float*)d_in[7];
  const float* Wv = (const float*)d_in[8];
  const float* bv = (const float*)d_in[9];
  float* out = (float*)d_out;

  unsigned short* ws16 = (unsigned short*)d_ws;
  unsigned short* WT  = ws16;                     // 3*65536 u16
  unsigned short* qs  = WT + 3 * 65536;           // 16384*64
  unsigned short* kh  = qs + 16384 * 64;          // 16384*64
  unsigned short* vhT = kh + 16384 * 64;          // 4*64*4096
  float* O_part = (float*)(vhT + 16384 * 64);

  const size_t base_bytes = (size_t)(3 * 65536 + 3 * 16384 * 64) * 2;
  int splits = 8;
  if (ws_size < base_bytes + (size_t)8 * 16384 * 65 * 4) splits = 4;
  float* L_part = O_part + (size_t)splits * 16384 * 64;
  const int nkt = 64 / splits;   // 64-key tiles per split

  transpose_w<<<dim3(768), dim3(256), 0, stream>>>(Wq, Wk, Wv, WT);
  proj_kernel<<<dim3(768), dim3(256), 0, stream>>>(q, k, v, m, bq, bk, bv, WT,
                                                   qs, kh, vhT);
  attn_split<<<dim3(splits * 256), dim3(256), 0, stream>>>(qs, kh, vhT,
                                                           O_part, L_part, nkt);
  attn_reduce<<<dim3(4096), dim3(256), 0, stream>>>(O_part, L_part, out, splits);
}